// Round 12
// baseline (240.988 us; speedup 1.0000x reference)
//
#include <hip/hip_runtime.h>
#include <hip/hip_cooperative_groups.h>

namespace cg = cooperative_groups;

#define NN 100000
#define NE 1600000
#define C 32

#define SHIFT 8
#define BINW 256                              // nodes per bin
#define NBIN ((NN + BINW - 1) / BINW)         // 391
#define EPB 4096                              // edges per chunk
#define NCHK ((NE + EPB - 1) / EPB)           // 391 chunks == grid size
#define SLACK 36                              // slots/(chunk,bin); lambda=10.5, P(ovf)~2e-5
#define QPC (SLACK / 4)                       // 9 int4 quads per cell
#define CAPT (NCHK * SLACK)                   // 14076 tmp slots per bin (%4==0)
#define SCAP 5120                             // LDS sorted-list capacity (4096+16sigma)

__device__ __forceinline__ unsigned bf16rne(float f) {
    unsigned u = __float_as_uint(f);
    return (u + 0x7fffu + ((u >> 16) & 1u)) >> 16;
}
__device__ __forceinline__ float blo(unsigned u) { return __uint_as_float(u << 16); }
__device__ __forceinline__ float bhi(unsigned u) { return __uint_as_float(u & 0xffff0000u); }

// Single cooperative mega-kernel: bin -> [grid sync] -> hist+place+linear
// -> [grid sync] -> gather. lsort/cnt/lbase persist in LDS across the
// second sync (same block), deleting placeAgg's global re-derivation.
__global__ __launch_bounds__(512, 4) void k_mega(const int* __restrict__ ei,
                                                 const float* __restrict__ x,
                                                 const float* __restrict__ W,
                                                 const float* __restrict__ bias,
                                                 int* __restrict__ tmp,
                                                 int* __restrict__ cfill,
                                                 unsigned* __restrict__ hu,
                                                 float* __restrict__ out) {
    __shared__ int ccnt[NBIN];                // ph1: bin cursors; ph2: chunk fills
    __shared__ int cnt[BINW];                 // per-node degree (LDS only)
    __shared__ int lbase[BINW];
    __shared__ int lcur[BINW];
    __shared__ int wtot[4], wbase[4];
    __shared__ float Ws[C][C + 1];            // 4.2KB
    __shared__ float xs[BINW][C];             // 32KB
    __shared__ int lsort[SCAP];               // 20.5KB; total ~60.7KB
    cg::grid_group grid = cg::this_grid();
    int blk = blockIdx.x, t = threadIdx.x;

    // ---------- phase 1: scatter chunk blk into chunk-partitioned bins ----
    if (t < NBIN) ccnt[t] = t * CAPT + blk * SLACK;
    __syncthreads();
    {
        int e0 = blk * EPB, e1 = min(e0 + EPB, NE);   // windows %4 == 0
        const int4* src4 = (const int4*)ei;
        const int4* col4 = (const int4*)(ei + NE);
        for (int q = (e0 >> 2) + t; q < (e1 >> 2); q += 512) {
            int4 s = src4[q];
            int4 c = col4[q];
            int p0 = atomicAdd(&ccnt[c.x >> SHIFT], 1);
            tmp[p0] = (s.x << SHIFT) | (c.x & (BINW - 1));
            int p1 = atomicAdd(&ccnt[c.y >> SHIFT], 1);
            tmp[p1] = (s.y << SHIFT) | (c.y & (BINW - 1));
            int p2 = atomicAdd(&ccnt[c.z >> SHIFT], 1);
            tmp[p2] = (s.z << SHIFT) | (c.z & (BINW - 1));
            int p3 = atomicAdd(&ccnt[c.w >> SHIFT], 1);
            tmp[p3] = (s.w << SHIFT) | (c.w & (BINW - 1));
        }
    }
    __syncthreads();
    if (t < NBIN)                             // [blk][i]: coalesced write
        cfill[blk * NBIN + t] = ccnt[t] - (t * CAPT + blk * SLACK);

    grid.sync();                              // all tmp/cfill visible

    // ---------- phase 2: own bin == blk: hist + scan + place + linear ----
    int bin = blk;
    if (t < NBIN) ccnt[t] = cfill[t * NBIN + bin];
    if (t < BINW) cnt[t] = 0;
    Ws[t >> 5][t & 31] = W[t];                // 1024 floats over 512 thr
    Ws[(t + 512) >> 5][t & 31] = W[t + 512];
    for (int i = t; i < BINW * C; i += 512) {
        int idx = (bin << SHIFT) * C + i;     // coalesced 32KB x-rows
        xs[i >> 5][i & 31] = (idx < NN * C) ? x[idx] : 0.0f;
    }
    __syncthreads();
    const int4* tp4 = (const int4*)tmp + bin * (CAPT >> 2);
    for (int q = t; q < (CAPT >> 2); q += 512) {      // hist walk (quad-skip)
        int chunk = q / QPC;                  // magic-mul division
        int off = (q - chunk * QPC) << 2;
        int fill = ccnt[chunk];
        if (off < fill) {
            int4 v = tp4[q];
            atomicAdd(&cnt[v.x & (BINW - 1)], 1);
            if (off + 1 < fill) atomicAdd(&cnt[v.y & (BINW - 1)], 1);
            if (off + 2 < fill) atomicAdd(&cnt[v.z & (BINW - 1)], 1);
            if (off + 3 < fill) atomicAdd(&cnt[v.w & (BINW - 1)], 1);
        }
    }
    __syncthreads();
    int lane = t & 63, w4 = t >> 6;           // scan of 256 degs (waves 0..3)
    int cv = 0, v = 0;
    if (t < BINW) {
        cv = cnt[t];
        v = cv;
#pragma unroll
        for (int d = 1; d < 64; d <<= 1) {
            int u = __shfl_up(v, d);
            if (lane >= d) v += u;
        }
        if (lane == 63) wtot[w4] = v;
    }
    __syncthreads();
    if (t == 0) {
        int r = 0;
#pragma unroll
        for (int k = 0; k < 4; ++k) { wbase[k] = r; r += wtot[k]; }
    }
    __syncthreads();
    if (t < BINW) {
        int loc = wbase[w4] + v - cv;
        lbase[t] = loc;
        lcur[t] = loc;
    }
    __syncthreads();
    for (int q = t; q < (CAPT >> 2); q += 512) {      // place walk (L2-hot)
        int chunk = q / QPC;
        int off = (q - chunk * QPC) << 2;
        int fill = ccnt[chunk];
        if (off < fill) {
            int4 e = tp4[q];
            lsort[atomicAdd(&lcur[e.x & (BINW - 1)], 1)] = e.x >> SHIFT;
            if (off + 1 < fill) lsort[atomicAdd(&lcur[e.y & (BINW - 1)], 1)] = e.y >> SHIFT;
            if (off + 2 < fill) lsort[atomicAdd(&lcur[e.z & (BINW - 1)], 1)] = e.z >> SHIFT;
            if (off + 3 < fill) lsort[atomicAdd(&lcur[e.w & (BINW - 1)], 1)] = e.w >> SHIFT;
        }
    }
    {   // linear: hu = bf16(rsqrt(1+deg) * xW^T); overlaps place-walk tail
        int m = t & 15, nl0 = t >> 4;         // 32 node-slots x 16 ch-pairs
#pragma unroll
        for (int rep = 0; rep < 8; ++rep) {
            int nl = nl0 + (rep << 5);
            int node = (bin << SHIFT) + nl;
            if (node < NN) {
                float a0 = 0.0f, a1 = 0.0f;
#pragma unroll
                for (int k = 0; k < C; ++k) {
                    float xv = xs[nl][k];
                    a0 += xv * Ws[2 * m][k];
                    a1 += xv * Ws[2 * m + 1][k];
                }
                float d = rsqrtf(1.0f + (float)cnt[nl]);   // incl. self-loop
                hu[node * 16 + m] = bf16rne(a0 * d) | (bf16rne(a1 * d) << 16);
            }
        }
    }

    grid.sync();                              // all hu visible

    // ---------- phase 3: gather (lsort/cnt/lbase still in LDS) ----------
    const uint4* hu4 = (const uint4*)hu;
    int g = t >> 2, m = t & 3;                // 128 groups x 4 lanes
#pragma unroll
    for (int rr = 0; rr < 2; ++rr) {
        int loc = g + rr * 128;
        int node = (bin << SHIFT) + loc;
        int beg = lbase[loc], cdeg = cnt[loc];
        float s0 = 0.0f, s1 = 0.0f, s2 = 0.0f, s3 = 0.0f;
        float s4 = 0.0f, s5 = 0.0f, s6 = 0.0f, s7 = 0.0f;
        int j = beg, jend = beg + cdeg;
        for (; j + 3 < jend; j += 4) {        // 4 rows in flight per lane
            int r0 = lsort[j], r1 = lsort[j + 1], r2 = lsort[j + 2], r3 = lsort[j + 3];
            uint4 u0 = hu4[r0 * 4 + m];
            uint4 u1 = hu4[r1 * 4 + m];
            uint4 u2 = hu4[r2 * 4 + m];
            uint4 u3 = hu4[r3 * 4 + m];
            s0 += blo(u0.x); s1 += bhi(u0.x); s2 += blo(u0.y); s3 += bhi(u0.y);
            s4 += blo(u0.z); s5 += bhi(u0.z); s6 += blo(u0.w); s7 += bhi(u0.w);
            s0 += blo(u1.x); s1 += bhi(u1.x); s2 += blo(u1.y); s3 += bhi(u1.y);
            s4 += blo(u1.z); s5 += bhi(u1.z); s6 += blo(u1.w); s7 += bhi(u1.w);
            s0 += blo(u2.x); s1 += bhi(u2.x); s2 += blo(u2.y); s3 += bhi(u2.y);
            s4 += blo(u2.z); s5 += bhi(u2.z); s6 += blo(u2.w); s7 += bhi(u2.w);
            s0 += blo(u3.x); s1 += bhi(u3.x); s2 += blo(u3.y); s3 += bhi(u3.y);
            s4 += blo(u3.z); s5 += bhi(u3.z); s6 += blo(u3.w); s7 += bhi(u3.w);
        }
        for (; j < jend; ++j) {
            uint4 u = hu4[lsort[j] * 4 + m];
            s0 += blo(u.x); s1 += bhi(u.x); s2 += blo(u.y); s3 += bhi(u.y);
            s4 += blo(u.z); s5 += bhi(u.z); s6 += blo(u.w); s7 += bhi(u.w);
        }
        if (node < NN) {
            float dn = rsqrtf(1.0f + (float)cdeg);
            uint4 us = hu4[node * 4 + m];     // self-loop row (pre-scaled)
            float4 b0 = ((const float4*)bias)[2 * m];
            float4 b1 = ((const float4*)bias)[2 * m + 1];
            float4 o0, o1;
            o0.x = b0.x + dn * (s0 + blo(us.x));
            o0.y = b0.y + dn * (s1 + bhi(us.x));
            o0.z = b0.z + dn * (s2 + blo(us.y));
            o0.w = b0.w + dn * (s3 + bhi(us.y));
            o1.x = b1.x + dn * (s4 + blo(us.z));
            o1.y = b1.y + dn * (s5 + bhi(us.z));
            o1.z = b1.z + dn * (s6 + blo(us.w));
            o1.w = b1.w + dn * (s7 + bhi(us.w));
            ((float4*)out)[node * 8 + 2 * m] = o0;
            ((float4*)out)[node * 8 + 2 * m + 1] = o1;
        }
    }
}

// ---------------- launch ----------------

extern "C" void kernel_launch(void* const* d_in, const int* in_sizes, int n_in,
                              void* d_out, int out_size, void* d_ws, size_t ws_size,
                              hipStream_t stream) {
    const float* x  = (const float*)d_in[0];
    const int*   ei = (const int*)d_in[1];
    const float* W  = (const float*)d_in[2];
    const float* b  = (const float*)d_in[3];
    float* out = (float*)d_out;

    // ws (~29 MB of 256 MB pool) — no overlays, all buffers distinct
    char* ws = (char*)d_ws;
    size_t o = 0;
    int*      tmp   = (int*)(ws + o);      o += (size_t)NBIN * CAPT * 4;   o = (o + 255) & ~(size_t)255;
    unsigned* hu    = (unsigned*)(ws + o); o += (size_t)NN * 16 * 4;       o = (o + 255) & ~(size_t)255;
    int*      cfill = (int*)(ws + o);

    void* args[] = { (void*)&ei, (void*)&x, (void*)&W, (void*)&b,
                     (void*)&tmp, (void*)&cfill, (void*)&hu, (void*)&out };
    hipLaunchCooperativeKernel((const void*)k_mega, dim3(NBIN), dim3(512),
                               args, 0, stream);
}

// Round 13
// 124.263 us; speedup vs baseline: 1.9393x; 1.9393x over previous
//
#include <hip/hip_runtime.h>

#define NN 100000
#define NE 1600000
#define C 32

#define SHIFT 7
#define BINW 128                              // nodes per bin (fine grain: R12 lesson)
#define NBIN ((NN + BINW - 1) / BINW)         // 782 -> ~3 blocks/CU for per-bin kernels
#define EPB 8192                              // edges per chunk (binning)
#define NCHK ((NE + EPB - 1) / EPB)           // 196 chunks = k_bin blocks
#define SLACK 32                              // slots/(chunk,bin); lambda=10.5, 1 line/cell
#define QPC 8                                 // int4 quads per cell (SLACK/4) -> shifts
#define CAPT (NCHK * SLACK)                   // 6272 tmp slots per bin
#define SCAP 2560                             // LDS sorted-list cap (2048 + 11 sigma)

__device__ __forceinline__ unsigned bf16rne(float f) {
    unsigned u = __float_as_uint(f);
    return (u + 0x7fffu + ((u >> 16) & 1u)) >> 16;
}
__device__ __forceinline__ float blo(unsigned u) { return __uint_as_float(u << 16); }
__device__ __forceinline__ float bhi(unsigned u) { return __uint_as_float(u & 0xffff0000u); }

// ---------------- kernels ----------------

// single-pass scatter into chunk-partitioned bins. Block b statically owns
// slots [bin*CAPT + b*32, +32) of every bin — each cell exactly one 128B line.
__global__ __launch_bounds__(1024) void k_bin(const int* __restrict__ ei,
                                              int* __restrict__ tmp,
                                              int* __restrict__ cfill) {
    __shared__ int lcur[NBIN];
    int b = blockIdx.x, t = threadIdx.x;
    if (t < NBIN) lcur[t] = t * CAPT + (b << 5);
    __syncthreads();
    int e0 = b * EPB, e1 = min(e0 + EPB, NE);   // windows %4 == 0
    const int4* src4 = (const int4*)ei;
    const int4* col4 = (const int4*)(ei + NE);
    for (int q = (e0 >> 2) + t; q < (e1 >> 2); q += 1024) {
        int4 s = src4[q];
        int4 c = col4[q];
        int p0 = atomicAdd(&lcur[c.x >> SHIFT], 1);
        tmp[p0] = (s.x << SHIFT) | (c.x & (BINW - 1));
        int p1 = atomicAdd(&lcur[c.y >> SHIFT], 1);
        tmp[p1] = (s.y << SHIFT) | (c.y & (BINW - 1));
        int p2 = atomicAdd(&lcur[c.z >> SHIFT], 1);
        tmp[p2] = (s.z << SHIFT) | (c.z & (BINW - 1));
        int p3 = atomicAdd(&lcur[c.w >> SHIFT], 1);
        tmp[p3] = (s.w << SHIFT) | (c.w & (BINW - 1));
    }
    __syncthreads();
    if (t < NBIN)                               // [b][i]: coalesced write
        cfill[b * NBIN + t] = lcur[t] - (t * CAPT + (b << 5));
}

// fused degree + linear: one block per (128-node) bin, 512 threads.
// Quad-skip walk (validity known pre-load; chunk math is shifts).
__global__ __launch_bounds__(512) void k_degLin(const int* __restrict__ cfill,
                                                const int* __restrict__ tmp,
                                                const float* __restrict__ x,
                                                const float* __restrict__ W,
                                                int* __restrict__ deg,
                                                unsigned* __restrict__ hu) {
    __shared__ int ccnt[NCHK];
    __shared__ int cnt[BINW];
    __shared__ float Ws[C][C + 1];
    __shared__ float xs[BINW][C];              // 16KB; total LDS ~21.7KB
    int bin = blockIdx.x, t = threadIdx.x;
    if (t < NCHK) ccnt[t] = cfill[t * NBIN + bin];
    if (t < BINW) cnt[t] = 0;
    Ws[t >> 5][t & 31] = W[t];                 // 1024 floats over 512 thr
    Ws[(t + 512) >> 5][t & 31] = W[t + 512];
    for (int i = t; i < BINW * C; i += 512) {
        int idx = (bin << SHIFT) * C + i;      // coalesced 16KB x-rows
        xs[i >> 5][i & 31] = (idx < NN * C) ? x[idx] : 0.0f;
    }
    __syncthreads();
    const int4* tp4 = (const int4*)tmp + bin * (CAPT >> 2);
    for (int q = t; q < (CAPT >> 2); q += 512) {
        int chunk = q >> 3;                    // QPC = 8
        int off = (q & 7) << 2;
        int fill = ccnt[chunk];
        if (off < fill) {                      // skip empty quads pre-load
            int4 v = tp4[q];
            atomicAdd(&cnt[v.x & (BINW - 1)], 1);
            if (off + 1 < fill) atomicAdd(&cnt[v.y & (BINW - 1)], 1);
            if (off + 2 < fill) atomicAdd(&cnt[v.z & (BINW - 1)], 1);
            if (off + 3 < fill) atomicAdd(&cnt[v.w & (BINW - 1)], 1);
        }
    }
    __syncthreads();
    if (t < BINW) {
        int node = (bin << SHIFT) + t;
        if (node < NN) deg[node] = cnt[t];     // for placeAgg's scan
    }
    int m = t & 15, nl0 = t >> 4;              // 32 node-slots x 16 ch-pairs
#pragma unroll
    for (int rep = 0; rep < 4; ++rep) {
        int nl = nl0 + (rep << 5);
        int node = (bin << SHIFT) + nl;
        if (node < NN) {
            float a0 = 0.0f, a1 = 0.0f;
#pragma unroll
            for (int k = 0; k < C; ++k) {
                float xv = xs[nl][k];
                a0 += xv * Ws[2 * m][k];
                a1 += xv * Ws[2 * m + 1][k];
            }
            float d = rsqrtf(1.0f + (float)cnt[nl]);   // incl. self-loop
            hu[node * 16 + m] = bf16rne(a0 * d) | (bf16rne(a1 * d) << 16);
        }
    }
}

// fused place+aggregate: one block per (128-node) bin, 512 threads.
// Reads deg -> scan -> place into LDS (quad-skip walk) -> 4-lane-group
// uint4 gather (one wave-instr covers 16 edge rows).
__global__ __launch_bounds__(512) void k_placeAgg(const int* __restrict__ cfill,
                                                  const int* __restrict__ tmp,
                                                  const int* __restrict__ deg,
                                                  const uint4* __restrict__ hu4,
                                                  const float* __restrict__ b,
                                                  float* __restrict__ out) {
    __shared__ int ccnt[NCHK];
    __shared__ int dg[BINW];
    __shared__ int lbase[BINW];
    __shared__ int lcur[BINW];
    __shared__ int lsort[SCAP];               // 10KB; total LDS ~12.8KB
    __shared__ int wtot[2];
    int bin = blockIdx.x, t = threadIdx.x;
    if (t < NCHK) ccnt[t] = cfill[t * NBIN + bin];
    if (t < BINW) {
        int node = (bin << SHIFT) + t;
        dg[t] = (node < NN) ? deg[node] : 0;   // coalesced, L2-hot
    }
    __syncthreads();
    // exclusive scan of 128 degs (threads 0..127 = waves 0..1)
    int lane = t & 63, w2 = t >> 6;
    int cv = 0, v = 0;
    if (t < BINW) {
        cv = dg[t];
        v = cv;
#pragma unroll
        for (int d = 1; d < 64; d <<= 1) {
            int u = __shfl_up(v, d);
            if (lane >= d) v += u;
        }
        if (lane == 63) wtot[w2] = v;
    }
    __syncthreads();
    if (t < BINW) {
        int loc = (w2 ? wtot[0] : 0) + v - cv; // exclusive local offset
        lbase[t] = loc;
        lcur[t] = loc;
    }
    __syncthreads();
    // place: quad-skip int4 walk of the gapped segment into LDS sorted list
    const int4* tp4 = (const int4*)tmp + bin * (CAPT >> 2);
    for (int q = t; q < (CAPT >> 2); q += 512) {
        int chunk = q >> 3;
        int off = (q & 7) << 2;
        int fill = ccnt[chunk];
        if (off < fill) {
            int4 e = tp4[q];
            lsort[atomicAdd(&lcur[e.x & (BINW - 1)], 1)] = e.x >> SHIFT;
            if (off + 1 < fill) lsort[atomicAdd(&lcur[e.y & (BINW - 1)], 1)] = e.y >> SHIFT;
            if (off + 2 < fill) lsort[atomicAdd(&lcur[e.z & (BINW - 1)], 1)] = e.z >> SHIFT;
            if (off + 3 < fill) lsort[atomicAdd(&lcur[e.w & (BINW - 1)], 1)] = e.w >> SHIFT;
        }
    }
    __syncthreads();
    // gather: 4-lane group per node (128 groups == all nodes, one pass);
    // lane m covers channels 8m..8m+7 via one uint4 per edge row.
    int g = t >> 2, m = t & 3;
    int beg = lbase[g], cnt = dg[g];
    float s0 = 0.0f, s1 = 0.0f, s2 = 0.0f, s3 = 0.0f;
    float s4 = 0.0f, s5 = 0.0f, s6 = 0.0f, s7 = 0.0f;
    int j = beg, jend = beg + cnt;
    for (; j + 3 < jend; j += 4) {             // 4 rows in flight per lane
        int r0 = lsort[j], r1 = lsort[j + 1], r2 = lsort[j + 2], r3 = lsort[j + 3];
        uint4 u0 = hu4[r0 * 4 + m];
        uint4 u1 = hu4[r1 * 4 + m];
        uint4 u2 = hu4[r2 * 4 + m];
        uint4 u3 = hu4[r3 * 4 + m];
        s0 += blo(u0.x); s1 += bhi(u0.x); s2 += blo(u0.y); s3 += bhi(u0.y);
        s4 += blo(u0.z); s5 += bhi(u0.z); s6 += blo(u0.w); s7 += bhi(u0.w);
        s0 += blo(u1.x); s1 += bhi(u1.x); s2 += blo(u1.y); s3 += bhi(u1.y);
        s4 += blo(u1.z); s5 += bhi(u1.z); s6 += blo(u1.w); s7 += bhi(u1.w);
        s0 += blo(u2.x); s1 += bhi(u2.x); s2 += blo(u2.y); s3 += bhi(u2.y);
        s4 += blo(u2.z); s5 += bhi(u2.z); s6 += blo(u2.w); s7 += bhi(u2.w);
        s0 += blo(u3.x); s1 += bhi(u3.x); s2 += blo(u3.y); s3 += bhi(u3.y);
        s4 += blo(u3.z); s5 += bhi(u3.z); s6 += blo(u3.w); s7 += bhi(u3.w);
    }
    for (; j < jend; ++j) {
        uint4 u = hu4[lsort[j] * 4 + m];
        s0 += blo(u.x); s1 += bhi(u.x); s2 += blo(u.y); s3 += bhi(u.y);
        s4 += blo(u.z); s5 += bhi(u.z); s6 += blo(u.w); s7 += bhi(u.w);
    }
    int node = (bin << SHIFT) + g;
    if (node < NN) {
        float dn = rsqrtf(1.0f + (float)cnt);
        uint4 us = hu4[node * 4 + m];          // self-loop row (pre-scaled)
        float4 b0 = ((const float4*)b)[2 * m];
        float4 b1 = ((const float4*)b)[2 * m + 1];
        float4 o0, o1;
        o0.x = b0.x + dn * (s0 + blo(us.x));
        o0.y = b0.y + dn * (s1 + bhi(us.x));
        o0.z = b0.z + dn * (s2 + blo(us.y));
        o0.w = b0.w + dn * (s3 + bhi(us.y));
        o1.x = b1.x + dn * (s4 + blo(us.z));
        o1.y = b1.y + dn * (s5 + bhi(us.z));
        o1.z = b1.z + dn * (s6 + blo(us.w));
        o1.w = b1.w + dn * (s7 + bhi(us.w));
        ((float4*)out)[node * 8 + 2 * m] = o0;
        ((float4*)out)[node * 8 + 2 * m + 1] = o1;
    }
}

// ---------------- launch ----------------

extern "C" void kernel_launch(void* const* d_in, const int* in_sizes, int n_in,
                              void* d_out, int out_size, void* d_ws, size_t ws_size,
                              hipStream_t stream) {
    const float* x  = (const float*)d_in[0];
    const int*   ei = (const int*)d_in[1];
    const float* W  = (const float*)d_in[2];
    const float* b  = (const float*)d_in[3];
    float* out = (float*)d_out;

    // ws (~27 MB of 256 MB pool) — no overlays, all buffers distinct
    char* ws = (char*)d_ws;
    size_t o = 0;
    int*      tmp   = (int*)(ws + o);      o += (size_t)NBIN * CAPT * 4;   o = (o + 255) & ~(size_t)255;
    unsigned* hu    = (unsigned*)(ws + o); o += (size_t)NN * 16 * 4;       o = (o + 255) & ~(size_t)255;
    int*      cfill = (int*)(ws + o);      o += (size_t)NCHK * NBIN * 4;   o = (o + 255) & ~(size_t)255;
    int*      deg   = (int*)(ws + o);

    k_bin<<<NCHK, 1024, 0, stream>>>(ei, tmp, cfill);
    k_degLin<<<NBIN, 512, 0, stream>>>(cfill, tmp, x, W, deg, hu);
    k_placeAgg<<<NBIN, 512, 0, stream>>>(cfill, tmp, deg, (const uint4*)hu, b, out);
}